// Round 6
// baseline (632.176 us; speedup 1.0000x reference)
//
#include <hip/hip_runtime.h>

#define NTOP 256

typedef __attribute__((ext_vector_type(8))) short bf16x8;
typedef __attribute__((ext_vector_type(4))) float f32x4;

// round-to-nearest-even bf16 high half of x
__device__ inline unsigned int rne_hi(float x) {
  unsigned int u = __float_as_uint(x);
  return (u + 0x7fffu + ((u >> 16) & 1u)) & 0xffff0000u;
}

__device__ inline float tanh_fast(float x) {
  float e = __expf(2.f * x);
  return 1.f - 2.f / (e + 1.f);
}

template <int CTRL>
__device__ inline float dpp_f(float v) {
  return __int_as_float(__builtin_amdgcn_update_dpp(
      0, __float_as_int(v), CTRL, 0xf, 0xf, true));
}

// inclusive prefix sum within each 16-lane row
__device__ inline float scan16(float v) {
  float s = v;
  s += dpp_f<0x111>(s);  // row_shr:1
  s += dpp_f<0x112>(s);  // row_shr:2
  s += dpp_f<0x114>(s);  // row_shr:4
  s += dpp_f<0x118>(s);  // row_shr:8
  return s;
}

__device__ inline void gload16(const void* g, void* l) {
  __builtin_amdgcn_global_load_lds(
      (const __attribute__((address_space(1))) unsigned int*)g,
      (__attribute__((address_space(3))) unsigned int*)l, 16, 0, 0);
}

// ---------------------------------------------------------------- K1
// 512 thr: j = tid>>1 (output), half = tid&1 (k-half). w[32] float4 in
// regs; 4 independent fmaf chains; DPP pair-reduce; tanh_fast; 1
// barrier/step. NO per-step global stores: h rows accumulate in LDS
// hist[16][256]; every 16 steps a cooperative dump writes the
// PRE-SWIZZLED bf16 hi/lo chunk images (chunk kc = [256 rows][128 B:
// hi64|lo64], byte^=((row&7)<<4)) — one vmcnt drain per 16 steps.
__global__ __launch_bounds__(512) void rsbc_recur(
    const float* __restrict__ Wih, const float* __restrict__ Whh,
    const float* __restrict__ bih, const float* __restrict__ bhh,
    const float* __restrict__ h0, char* __restrict__ Hws) {
  __shared__ float hA[NTOP], hB[NTOP];
  __shared__ float hist[16][NTOP];
  const int tid = threadIdx.x;
  const int j = tid >> 1, half = tid & 1, k0 = half << 7;
  const float bj = bih[j] + bhh[j];

  float4 w[32];
  {
    const float4* wp = reinterpret_cast<const float4*>(Wih + j * NTOP + k0);
#pragma unroll
    for (int q = 0; q < 32; ++q) w[q] = wp[q];
  }
  if (tid < NTOP) hA[tid] = h0[tid];
  if (tid < 64) {  // zero row 255 of each chunk image
    int kc = tid >> 3, gd = tid & 7;
    *reinterpret_cast<uint4*>(Hws + kc * 32768 + 255 * 128 + gd * 16) =
        make_uint4(0u, 0u, 0u, 0u);
  }
  __syncthreads();

  // step 0: h1 = tanh(h0 @ Wih^T + b)
  {
    const float* hq = hA + k0;
    float a0 = 0.f, a1 = 0.f, a2 = 0.f, a3 = 0.f;
#pragma unroll
    for (int q = 0; q < 32; ++q) {
      float4 hv = *reinterpret_cast<const float4*>(hq + 4 * q);
      a0 = fmaf(hv.x, w[q].x, a0);
      a1 = fmaf(hv.y, w[q].y, a1);
      a2 = fmaf(hv.z, w[q].z, a2);
      a3 = fmaf(hv.w, w[q].w, a3);
    }
    float sv = (a0 + a1) + (a2 + a3);
    sv += dpp_f<0xB1>(sv);               // + lane^1
    if (half == 0) {
      float v = tanh_fast(sv + bj);
      hB[j] = v;
      hist[0][j] = v;
    }
  }
  // Wc = W_ih + W_hh
  {
    const float4* wq = reinterpret_cast<const float4*>(Whh + j * NTOP + k0);
#pragma unroll
    for (int q = 0; q < 32; ++q) {
      float4 t = wq[q];
      w[q].x += t.x; w[q].y += t.y; w[q].z += t.z; w[q].w += t.w;
    }
  }
  __syncthreads();

#pragma unroll 1
  for (int s = 1; s < 255; ++s) {
    const float* hr = (s & 1) ? hB : hA;
    float* hw = (s & 1) ? hA : hB;
    const float* hq = hr + k0;
    float a0 = 0.f, a1 = 0.f, a2 = 0.f, a3 = 0.f;
#pragma unroll
    for (int q = 0; q < 32; ++q) {
      float4 hv = *reinterpret_cast<const float4*>(hq + 4 * q);
      a0 = fmaf(hv.x, w[q].x, a0);
      a1 = fmaf(hv.y, w[q].y, a1);
      a2 = fmaf(hv.z, w[q].z, a2);
      a3 = fmaf(hv.w, w[q].w, a3);
    }
    float sv = (a0 + a1) + (a2 + a3);
    sv += dpp_f<0xB1>(sv);
    if (half == 0) {
      float v = tanh_fast(sv + bj);
      hw[j] = v;
      hist[s & 15][j] = v;
    }
    __syncthreads();
    if ((s & 15) == 15) {
      // dump rows s-15..s (16 rows x 8 chunks x 8 granules of 16 B)
      const int s0 = s - 15;
#pragma unroll
      for (int half_i = 0; half_i < 2; ++half_i) {
        int i = tid + 512 * half_i;          // 0..1023
        int kc = i >> 7, sr = (i >> 3) & 15, gd = i & 7;
        int srow = s0 + sr;
        int gs = gd ^ (srow & 7);            // source granule (involution)
        int plane = gs >> 2;                 // 0=hi, 1=lo
        int tb = 32 * kc + 8 * (gs & 3);     // topic base
        float4 xa = *reinterpret_cast<const float4*>(&hist[sr][tb]);
        float4 xb = *reinterpret_cast<const float4*>(&hist[sr][tb + 4]);
        float xs[8] = {xa.x, xa.y, xa.z, xa.w, xb.x, xb.y, xb.z, xb.w};
        ushort us[8];
#pragma unroll
        for (int e = 0; e < 8; ++e) {
          unsigned int hi = rne_hi(xs[e]);
          if (plane == 0) {
            us[e] = (ushort)(hi >> 16);
          } else {
            float res = xs[e] - __uint_as_float(hi);
            us[e] = (ushort)(rne_hi(res) >> 16);
          }
        }
        *reinterpret_cast<uint4*>(Hws + kc * 32768 + srow * 128 + gd * 16) =
            *reinterpret_cast<const uint4*>(us);
      }
      __syncthreads();   // dump reads done before hist slots are reused
    }
  }
  // tail dump: rows 240..254 (15 rows, hist slots 0..14)
#pragma unroll
  for (int half_i = 0; half_i < 2; ++half_i) {
    int i = tid + 512 * half_i;
    int kc = i >> 7, sr = (i >> 3) & 15, gd = i & 7;
    if (sr < 15) {
      int srow = 240 + sr;
      int gs = gd ^ (srow & 7);
      int plane = gs >> 2;
      int tb = 32 * kc + 8 * (gs & 3);
      float4 xa = *reinterpret_cast<const float4*>(&hist[sr][tb]);
      float4 xb = *reinterpret_cast<const float4*>(&hist[sr][tb + 4]);
      float xs[8] = {xa.x, xa.y, xa.z, xa.w, xb.x, xb.y, xb.z, xb.w};
      ushort us[8];
#pragma unroll
      for (int e = 0; e < 8; ++e) {
        unsigned int hi = rne_hi(xs[e]);
        if (plane == 0) {
          us[e] = (ushort)(hi >> 16);
        } else {
          float res = xs[e] - __uint_as_float(hi);
          us[e] = (ushort)(rne_hi(res) >> 16);
        }
      }
      *reinterpret_cast<uint4*>(Hws + kc * 32768 + srow * 128 + gd * 16) =
          *reinterpret_cast<const uint4*>(us);
    }
  }
}

// ---------------------------------------------------------------- K2
// bf16x3 MFMA GEMM (Z @ H^T) + log-space stick-breaking.
// 512 thr (8 waves 2x4), BM=128, N=256, K-chunk=32 (8 chunks).
// A tile [128 rows][128 B: hi64|lo64], B tile [256 rows][128 B], both
// XOR-swizzled byte^=((row&7)<<4) -> frag reads bank-conflict-free.
// B arrives pre-swizzled from K1 via linear global_load_lds (rule #21:
// source permutation == read permutation). Epilogue: softplus + DPP
// scan16 + rowT fixup in regs; stores staged through LDS, full lines.
__global__ __launch_bounds__(512) void rsbc_gemm_sb(
    const float* __restrict__ z, const char* __restrict__ Hws,
    float* __restrict__ out) {
  __shared__ __align__(16) char smem[49152];
  __shared__ float rowT[128 * 5];
  char* Ab = smem;            // A: 128 x 128 B = 16 KB
  char* Bb = smem + 16384;    // B: 256 x 128 B = 32 KB

  const int tid = threadIdx.x;
  const size_t row0 = (size_t)blockIdx.x * 128;
  const int wid = tid >> 6, lane = tid & 63;
  const int wr = wid >> 2, wc = wid & 3;
  const int l15 = lane & 15, l4 = lane >> 4;

  f32x4 acc[4][4];
#pragma unroll
  for (int mt = 0; mt < 4; ++mt)
#pragma unroll
    for (int nt = 0; nt < 4; ++nt) acc[mt][nt] = (f32x4){0.f, 0.f, 0.f, 0.f};

  // prefetch z chunk 0
  float4 zpre[2];
#pragma unroll
  for (int it = 0; it < 2; ++it) {
    int idx = tid + 512 * it;
    int r = idx >> 3, q = idx & 7;
    zpre[it] = *reinterpret_cast<const float4*>(z + (row0 + r) * NTOP + 4 * q);
  }

  for (int kc = 0; kc < 8; ++kc) {
    __syncthreads();                  // prev chunk frag reads done
    // ---- A: convert prefetched z, swizzled hi/lo writes
#pragma unroll
    for (int it = 0; it < 2; ++it) {
      int idx = tid + 512 * it;
      int r = idx >> 3, q = idx & 7;
      int sw = (r & 7) << 4;
      float4 v = zpre[it];
      unsigned int h0i = rne_hi(v.x), h1i = rne_hi(v.y),
                   h2i = rne_hi(v.z), h3i = rne_hi(v.w);
      *reinterpret_cast<ushort4*>(Ab + r * 128 + ((8 * q) ^ sw)) =
          make_ushort4((ushort)(h0i >> 16), (ushort)(h1i >> 16),
                       (ushort)(h2i >> 16), (ushort)(h3i >> 16));
      float r0 = v.x - __uint_as_float(h0i), r1 = v.y - __uint_as_float(h1i);
      float r2 = v.z - __uint_as_float(h2i), r3 = v.w - __uint_as_float(h3i);
      *reinterpret_cast<ushort4*>(Ab + r * 128 + ((64 + 8 * q) ^ sw)) =
          make_ushort4((ushort)(rne_hi(r0) >> 16), (ushort)(rne_hi(r1) >> 16),
                       (ushort)(rne_hi(r2) >> 16), (ushort)(rne_hi(r3) >> 16));
    }
    // ---- B: async linear copy of pre-swizzled 32 KB chunk image
    {
      const char* src = Hws + kc * 32768;
#pragma unroll
      for (int it = 0; it < 4; ++it) {
        int off = (tid + 512 * it) * 16;
        gload16(src + off, Bb + off);
      }
    }
    // ---- prefetch next z chunk
    if (kc < 7) {
#pragma unroll
      for (int it = 0; it < 2; ++it) {
        int idx = tid + 512 * it;
        int r = idx >> 3, q = idx & 7;
        zpre[it] = *reinterpret_cast<const float4*>(
            z + (row0 + r) * NTOP + (kc + 1) * 32 + 4 * q);
      }
    }
    __syncthreads();                  // staged (vmcnt drained here)
    // ---- 48 MFMA (K=32, bf16x3), mt in pairs to cap reg pressure
#pragma unroll
    for (int mtp = 0; mtp < 2; ++mtp) {
      bf16x8 ah[2], al[2];
#pragma unroll
      for (int m = 0; m < 2; ++m) {
        int r = 64 * wr + 16 * (2 * mtp + m) + l15;
        int sw = (r & 7) << 4;
        ah[m] = *reinterpret_cast<const bf16x8*>(
            Ab + r * 128 + ((l4 * 16) ^ sw));
        al[m] = *reinterpret_cast<const bf16x8*>(
            Ab + r * 128 + ((64 + l4 * 16) ^ sw));
      }
#pragma unroll
      for (int nt = 0; nt < 4; ++nt) {
        int n = 64 * wc + 16 * nt + l15;
        int sw = (n & 7) << 4;
        bf16x8 bh = *reinterpret_cast<const bf16x8*>(
            Bb + n * 128 + ((l4 * 16) ^ sw));
        bf16x8 bl = *reinterpret_cast<const bf16x8*>(
            Bb + n * 128 + ((64 + l4 * 16) ^ sw));
#pragma unroll
        for (int m = 0; m < 2; ++m) {
          int mt = 2 * mtp + m;
          acc[mt][nt] = __builtin_amdgcn_mfma_f32_16x16x32_bf16(
              ah[m], bh, acc[mt][nt], 0, 0, 0);
          acc[mt][nt] = __builtin_amdgcn_mfma_f32_16x16x32_bf16(
              ah[m], bl, acc[mt][nt], 0, 0, 0);
          acc[mt][nt] = __builtin_amdgcn_mfma_f32_16x16x32_bf16(
              al[m], bh, acc[mt][nt], 0, 0, 0);
        }
      }
    }
  }

  // ---- epilogue pass A: zc, sp=softplus, in-register prefix scan
  // C layout: row = 64wr+16mt+4*l4+i, col = 64wc+16nt+l15
  float lt[4];
#pragma unroll
  for (int nt = 0; nt < 4; ++nt) {
    int col = 64 * wc + 16 * nt + l15;
    lt[nt] = (col < 255) ? __logf((float)(255 - col)) : 0.f;
  }
#pragma unroll
  for (int mt = 0; mt < 4; ++mt)
#pragma unroll
    for (int i = 0; i < 4; ++i) {
      float carry = 0.f;
#pragma unroll
      for (int nt = 0; nt < 4; ++nt) {
        float a = acc[mt][nt][i];
        float t1 = __expf(-a);
        float s1 = __builtin_amdgcn_rcpf(1.f + t1);   // sigmoid(logit)
        float x = s1 - lt[nt];
        float t = __expf(-x);
        float zc = __builtin_amdgcn_rcpf(1.f + t);    // sigmoid(x)
        float sp = x + __logf(1.f + t);               // softplus(x)
        if ((wc == 3) && (nt == 3) && (l15 == 15)) {  // col 255 dummy
          zc = 1.f; sp = 0.f;
        }
        float incl = scan16(sp);
        float Sl = carry + (incl - sp);               // exclusive prefix
        acc[mt][nt][i] = zc * __expf(-Sl);
        carry += __shfl(incl, 15, 16);
      }
      if (l15 == 0)
        rowT[(64 * wr + 16 * mt + 4 * l4 + i) * 5 + wc] = carry;
    }
  __syncthreads();   // rowT visible; staging LDS now dead -> reuse

  // ---- pass B: cross-wave offset, slice-staged full-line stores
  float* stage = reinterpret_cast<float*>(smem);      // [32][260]
#pragma unroll 1
  for (int mt = 0; mt < 4; ++mt) {
#pragma unroll
    for (int i = 0; i < 4; ++i) {
      int rl = 16 * wr + 4 * l4 + i;                  // row within slice
      int r = 64 * wr + 16 * mt + 4 * l4 + i;
      float ew = 1.f;
      if (wc > 0) {
        float W = rowT[r * 5 + 0];
        if (wc > 1) W += rowT[r * 5 + 1];
        if (wc > 2) W += rowT[r * 5 + 2];
        ew = __expf(-W);
      }
#pragma unroll
      for (int nt = 0; nt < 4; ++nt)
        stage[rl * 260 + 64 * wc + 16 * nt + l15] = acc[mt][nt][i] * ew;
    }
    __syncthreads();
#pragma unroll
    for (int it = 0; it < 4; ++it) {
      int idx = tid + 512 * it;        // 0..2047
      int rr = idx >> 6, cq = idx & 63;
      int grow = 64 * (rr >> 4) + 16 * mt + (rr & 15);
      float4 v4 = *reinterpret_cast<const float4*>(stage + rr * 260 + 4 * cq);
      *reinterpret_cast<float4*>(&out[(row0 + grow) * NTOP + 4 * cq]) = v4;
    }
    __syncthreads();
  }
}

// ---------------------------------------------------------------- launch
extern "C" void kernel_launch(void* const* d_in, const int* in_sizes, int n_in,
                              void* d_out, int out_size, void* d_ws, size_t ws_size,
                              hipStream_t stream) {
  const float* z   = (const float*)d_in[0];
  const float* h0  = (const float*)d_in[1];
  const float* Wih = (const float*)d_in[2];
  const float* Whh = (const float*)d_in[3];
  const float* bih = (const float*)d_in[4];
  const float* bhh = (const float*)d_in[5];
  float* out = (float*)d_out;
  char* Hws = (char*)d_ws;   // 8 chunks x 32 KB = 256 KB (pre-swizzled)

  rsbc_recur<<<1, 512, 0, stream>>>(Wih, Whh, bih, bhh, h0, Hws);
  const int nrows = out_size / NTOP;   // 131072
  const int blocks = nrows / 128;      // 1024
  rsbc_gemm_sb<<<blocks, 512, 0, stream>>>(z, Hws, out);
}

// Round 7
// 629.520 us; speedup vs baseline: 1.0042x; 1.0042x over previous
//
#include <hip/hip_runtime.h>

#define NTOP 256

typedef __attribute__((ext_vector_type(8))) short bf16x8;
typedef __attribute__((ext_vector_type(4))) float f32x4;

// round-to-nearest-even bf16 high half of x
__device__ inline unsigned int rne_hi(float x) {
  unsigned int u = __float_as_uint(x);
  return (u + 0x7fffu + ((u >> 16) & 1u)) & 0xffff0000u;
}

__device__ inline float tanh_fast(float x) {
  float e = __expf(2.f * x);
  return 1.f - 2.f / (e + 1.f);
}

template <int CTRL>
__device__ inline float dpp_f(float v) {
  return __int_as_float(__builtin_amdgcn_update_dpp(
      0, __float_as_int(v), CTRL, 0xf, 0xf, true));
}

// inclusive prefix sum within each 16-lane row
__device__ inline float scan16(float v) {
  float s = v;
  s += dpp_f<0x111>(s);  // row_shr:1
  s += dpp_f<0x112>(s);  // row_shr:2
  s += dpp_f<0x114>(s);  // row_shr:4
  s += dpp_f<0x118>(s);  // row_shr:8
  return s;
}

__device__ inline void gload16(const void* g, void* l) {
  __builtin_amdgcn_global_load_lds(
      (const __attribute__((address_space(1))) unsigned int*)g,
      (__attribute__((address_space(3))) unsigned int*)l, 16, 0, 0);
}

// ---------------------------------------------------------------- K1
// 512 thr: j = tid>>1 (output), half = tid&1 (k-half). w[32] float4 in
// regs — (512,1) launch bounds give the allocator a 256+ VGPR budget so
// w is REGISTER-RESIDENT (default heuristic was spilling it to scratch).
// 4 independent fmaf chains; DPP pair-reduce; tanh_fast; 1 barrier/step.
// h rows accumulate in LDS hist[16][256]; every 16 steps a cooperative
// dump writes the PRE-SWIZZLED bf16 hi/lo chunk images (chunk kc =
// [256 rows][128 B: hi64|lo64], byte^=((row&7)<<4)).
__global__ __launch_bounds__(512, 1) void rsbc_recur(
    const float* __restrict__ Wih, const float* __restrict__ Whh,
    const float* __restrict__ bih, const float* __restrict__ bhh,
    const float* __restrict__ h0, char* __restrict__ Hws) {
  __shared__ float hA[NTOP], hB[NTOP];
  __shared__ float hist[16][NTOP];
  const int tid = threadIdx.x;
  const int j = tid >> 1, half = tid & 1, k0 = half << 7;
  const float bj = bih[j] + bhh[j];

  float4 w[32];
  {
    const float4* wp = reinterpret_cast<const float4*>(Wih + j * NTOP + k0);
#pragma unroll
    for (int q = 0; q < 32; ++q) w[q] = wp[q];
  }
  if (tid < NTOP) hA[tid] = h0[tid];
  if (tid < 64) {  // zero row 255 of each chunk image
    int kc = tid >> 3, gd = tid & 7;
    *reinterpret_cast<uint4*>(Hws + kc * 32768 + 255 * 128 + gd * 16) =
        make_uint4(0u, 0u, 0u, 0u);
  }
  __syncthreads();

  // step 0: h1 = tanh(h0 @ Wih^T + b)
  {
    const float* hq = hA + k0;
    float a0 = 0.f, a1 = 0.f, a2 = 0.f, a3 = 0.f;
#pragma unroll
    for (int q = 0; q < 32; ++q) {
      float4 hv = *reinterpret_cast<const float4*>(hq + 4 * q);
      a0 = fmaf(hv.x, w[q].x, a0);
      a1 = fmaf(hv.y, w[q].y, a1);
      a2 = fmaf(hv.z, w[q].z, a2);
      a3 = fmaf(hv.w, w[q].w, a3);
    }
    float sv = (a0 + a1) + (a2 + a3);
    sv += dpp_f<0xB1>(sv);               // + lane^1
    if (half == 0) {
      float v = tanh_fast(sv + bj);
      hB[j] = v;
      hist[0][j] = v;
    }
  }
  // Wc = W_ih + W_hh
  {
    const float4* wq = reinterpret_cast<const float4*>(Whh + j * NTOP + k0);
#pragma unroll
    for (int q = 0; q < 32; ++q) {
      float4 t = wq[q];
      w[q].x += t.x; w[q].y += t.y; w[q].z += t.z; w[q].w += t.w;
    }
  }
  __syncthreads();

#pragma unroll 1
  for (int s = 1; s < 255; ++s) {
    const float* hr = (s & 1) ? hB : hA;
    float* hw = (s & 1) ? hA : hB;
    const float* hq = hr + k0;
    float a0 = 0.f, a1 = 0.f, a2 = 0.f, a3 = 0.f;
#pragma unroll
    for (int q = 0; q < 32; ++q) {
      float4 hv = *reinterpret_cast<const float4*>(hq + 4 * q);
      a0 = fmaf(hv.x, w[q].x, a0);
      a1 = fmaf(hv.y, w[q].y, a1);
      a2 = fmaf(hv.z, w[q].z, a2);
      a3 = fmaf(hv.w, w[q].w, a3);
    }
    float sv = (a0 + a1) + (a2 + a3);
    sv += dpp_f<0xB1>(sv);
    if (half == 0) {
      float v = tanh_fast(sv + bj);
      hw[j] = v;
      hist[s & 15][j] = v;
    }
    __syncthreads();
    if ((s & 15) == 15) {
      // dump rows s-15..s (16 rows x 8 chunks x 8 granules of 16 B)
      const int s0 = s - 15;
#pragma unroll
      for (int half_i = 0; half_i < 2; ++half_i) {
        int i = tid + 512 * half_i;          // 0..1023
        int kc = i >> 7, sr = (i >> 3) & 15, gd = i & 7;
        int srow = s0 + sr;
        int gs = gd ^ (srow & 7);            // source granule (involution)
        int plane = gs >> 2;                 // 0=hi, 1=lo
        int tb = 32 * kc + 8 * (gs & 3);     // topic base
        float4 xa = *reinterpret_cast<const float4*>(&hist[sr][tb]);
        float4 xb = *reinterpret_cast<const float4*>(&hist[sr][tb + 4]);
        float xs[8] = {xa.x, xa.y, xa.z, xa.w, xb.x, xb.y, xb.z, xb.w};
        ushort us[8];
#pragma unroll
        for (int e = 0; e < 8; ++e) {
          unsigned int hi = rne_hi(xs[e]);
          if (plane == 0) {
            us[e] = (ushort)(hi >> 16);
          } else {
            float res = xs[e] - __uint_as_float(hi);
            us[e] = (ushort)(rne_hi(res) >> 16);
          }
        }
        *reinterpret_cast<uint4*>(Hws + kc * 32768 + srow * 128 + gd * 16) =
            *reinterpret_cast<const uint4*>(us);
      }
      __syncthreads();   // dump reads done before hist slots are reused
    }
  }
  // tail dump: rows 240..254 (15 rows, hist slots 0..14)
#pragma unroll
  for (int half_i = 0; half_i < 2; ++half_i) {
    int i = tid + 512 * half_i;
    int kc = i >> 7, sr = (i >> 3) & 15, gd = i & 7;
    if (sr < 15) {
      int srow = 240 + sr;
      int gs = gd ^ (srow & 7);
      int plane = gs >> 2;
      int tb = 32 * kc + 8 * (gs & 3);
      float4 xa = *reinterpret_cast<const float4*>(&hist[sr][tb]);
      float4 xb = *reinterpret_cast<const float4*>(&hist[sr][tb + 4]);
      float xs[8] = {xa.x, xa.y, xa.z, xa.w, xb.x, xb.y, xb.z, xb.w};
      ushort us[8];
#pragma unroll
      for (int e = 0; e < 8; ++e) {
        unsigned int hi = rne_hi(xs[e]);
        if (plane == 0) {
          us[e] = (ushort)(hi >> 16);
        } else {
          float res = xs[e] - __uint_as_float(hi);
          us[e] = (ushort)(rne_hi(res) >> 16);
        }
      }
      *reinterpret_cast<uint4*>(Hws + kc * 32768 + srow * 128 + gd * 16) =
          *reinterpret_cast<const uint4*>(us);
    }
  }
}

// ---------------------------------------------------------------- K2
// bf16x3 MFMA GEMM (Z @ H^T) + log-space stick-breaking.
// 512 thr (8 waves 2x4), BM=64 (acc[2][4] = 32 floats/thread), N=256,
// K-chunk=32 (8 chunks). (512,4): explicit 128-VGPR budget — fits the
// ~95-reg live set, no spill. A tile [64][128 B hi|lo], B tile
// [256][128 B], both XOR-swizzled byte^=((row&7)<<4); B arrives
// pre-swizzled from K1 via linear global_load_lds. Register epilogue
// (softplus + scan16 + rowT fixup); LDS-staged full-line stores.
__global__ __launch_bounds__(512, 4) void rsbc_gemm_sb(
    const float* __restrict__ z, const char* __restrict__ Hws,
    float* __restrict__ out) {
  __shared__ __align__(16) char smem[40960];
  __shared__ float rowT[64 * 5];
  char* Ab = smem;            // A: 64 x 128 B = 8 KB
  char* Bb = smem + 8192;     // B: 256 x 128 B = 32 KB

  const int tid = threadIdx.x;
  const size_t row0 = (size_t)blockIdx.x * 64;
  const int wid = tid >> 6, lane = tid & 63;
  const int wr = wid >> 2, wc = wid & 3;
  const int l15 = lane & 15, l4 = lane >> 4;

  f32x4 acc[2][4];
#pragma unroll
  for (int mt = 0; mt < 2; ++mt)
#pragma unroll
    for (int nt = 0; nt < 4; ++nt) acc[mt][nt] = (f32x4){0.f, 0.f, 0.f, 0.f};

  const int pr = tid >> 3, pq = tid & 7;   // z staging: row, float4-idx
  // prefetch z chunk 0 (1 float4/thread)
  float4 zpre = *reinterpret_cast<const float4*>(z + (row0 + pr) * NTOP + 4 * pq);

  for (int kc = 0; kc < 8; ++kc) {
    __syncthreads();                  // prev chunk frag reads done
    // ---- A: convert prefetched z, swizzled hi/lo writes
    {
      int sw = (pr & 7) << 4;
      float4 v = zpre;
      unsigned int h0i = rne_hi(v.x), h1i = rne_hi(v.y),
                   h2i = rne_hi(v.z), h3i = rne_hi(v.w);
      *reinterpret_cast<ushort4*>(Ab + pr * 128 + ((8 * pq) ^ sw)) =
          make_ushort4((ushort)(h0i >> 16), (ushort)(h1i >> 16),
                       (ushort)(h2i >> 16), (ushort)(h3i >> 16));
      float r0 = v.x - __uint_as_float(h0i), r1 = v.y - __uint_as_float(h1i);
      float r2 = v.z - __uint_as_float(h2i), r3 = v.w - __uint_as_float(h3i);
      *reinterpret_cast<ushort4*>(Ab + pr * 128 + ((64 + 8 * pq) ^ sw)) =
          make_ushort4((ushort)(rne_hi(r0) >> 16), (ushort)(rne_hi(r1) >> 16),
                       (ushort)(rne_hi(r2) >> 16), (ushort)(rne_hi(r3) >> 16));
    }
    // ---- B: async linear copy of pre-swizzled 32 KB chunk image
    {
      const char* src = Hws + kc * 32768;
#pragma unroll
      for (int it = 0; it < 4; ++it) {
        int off = (tid + 512 * it) * 16;
        gload16(src + off, Bb + off);
      }
    }
    // ---- prefetch next z chunk
    if (kc < 7)
      zpre = *reinterpret_cast<const float4*>(
          z + (row0 + pr) * NTOP + (kc + 1) * 32 + 4 * pq);
    __syncthreads();                  // staged (vmcnt drained here)
    // ---- 24 MFMA (K=32, bf16x3)
    bf16x8 ah[2], al[2];
#pragma unroll
    for (int m = 0; m < 2; ++m) {
      int r = 32 * wr + 16 * m + l15;
      int sw = (r & 7) << 4;
      ah[m] = *reinterpret_cast<const bf16x8*>(Ab + r * 128 + ((l4 * 16) ^ sw));
      al[m] = *reinterpret_cast<const bf16x8*>(
          Ab + r * 128 + ((64 + l4 * 16) ^ sw));
    }
#pragma unroll
    for (int nt = 0; nt < 4; ++nt) {
      int n = 64 * wc + 16 * nt + l15;
      int sw = (n & 7) << 4;
      bf16x8 bh = *reinterpret_cast<const bf16x8*>(
          Bb + n * 128 + ((l4 * 16) ^ sw));
      bf16x8 bl = *reinterpret_cast<const bf16x8*>(
          Bb + n * 128 + ((64 + l4 * 16) ^ sw));
#pragma unroll
      for (int m = 0; m < 2; ++m) {
        acc[m][nt] = __builtin_amdgcn_mfma_f32_16x16x32_bf16(
            ah[m], bh, acc[m][nt], 0, 0, 0);
        acc[m][nt] = __builtin_amdgcn_mfma_f32_16x16x32_bf16(
            ah[m], bl, acc[m][nt], 0, 0, 0);
        acc[m][nt] = __builtin_amdgcn_mfma_f32_16x16x32_bf16(
            al[m], bh, acc[m][nt], 0, 0, 0);
      }
    }
  }

  // ---- epilogue pass A: zc, sp=softplus, in-register prefix scan
  // C layout: row = 32wr+16mt+4*l4+i, col = 64wc+16nt+l15
  float lt[4];
#pragma unroll
  for (int nt = 0; nt < 4; ++nt) {
    int col = 64 * wc + 16 * nt + l15;
    lt[nt] = (col < 255) ? __logf((float)(255 - col)) : 0.f;
  }
#pragma unroll
  for (int mt = 0; mt < 2; ++mt)
#pragma unroll
    for (int i = 0; i < 4; ++i) {
      float carry = 0.f;
#pragma unroll
      for (int nt = 0; nt < 4; ++nt) {
        float a = acc[mt][nt][i];
        float t1 = __expf(-a);
        float s1 = __builtin_amdgcn_rcpf(1.f + t1);   // sigmoid(logit)
        float x = s1 - lt[nt];
        float t = __expf(-x);
        float zc = __builtin_amdgcn_rcpf(1.f + t);    // sigmoid(x)
        float sp = x + __logf(1.f + t);               // softplus(x)
        if ((wc == 3) && (nt == 3) && (l15 == 15)) {  // col 255 dummy
          zc = 1.f; sp = 0.f;
        }
        float incl = scan16(sp);
        float Sl = carry + (incl - sp);               // exclusive prefix
        acc[mt][nt][i] = zc * __expf(-Sl);
        carry += __shfl(incl, 15, 16);
      }
      if (l15 == 0)
        rowT[(32 * wr + 16 * mt + 4 * l4 + i) * 5 + wc] = carry;
    }
  __syncthreads();   // rowT visible; staging LDS now dead -> reuse

  // ---- pass B: cross-wave offset, slice-staged full-line stores
  float* stage = reinterpret_cast<float*>(smem);      // [32][260]
#pragma unroll 1
  for (int mt = 0; mt < 2; ++mt) {
#pragma unroll
    for (int i = 0; i < 4; ++i) {
      int rl = 16 * wr + 4 * l4 + i;                  // row within slice
      int r = 32 * wr + 16 * mt + 4 * l4 + i;
      float ew = 1.f;
      if (wc > 0) {
        float W = rowT[r * 5 + 0];
        if (wc > 1) W += rowT[r * 5 + 1];
        if (wc > 2) W += rowT[r * 5 + 2];
        ew = __expf(-W);
      }
#pragma unroll
      for (int nt = 0; nt < 4; ++nt)
        stage[rl * 260 + 64 * wc + 16 * nt + l15] = acc[mt][nt][i] * ew;
    }
    __syncthreads();
#pragma unroll
    for (int it = 0; it < 4; ++it) {
      int idx = tid + 512 * it;        // 0..2047
      int rr = idx >> 6, cq = idx & 63;
      int grow = 32 * (rr >> 4) + 16 * mt + (rr & 15);
      float4 v4 = *reinterpret_cast<const float4*>(stage + rr * 260 + 4 * cq);
      *reinterpret_cast<float4*>(&out[(row0 + grow) * NTOP + 4 * cq]) = v4;
    }
    __syncthreads();
  }
}

// ---------------------------------------------------------------- launch
extern "C" void kernel_launch(void* const* d_in, const int* in_sizes, int n_in,
                              void* d_out, int out_size, void* d_ws, size_t ws_size,
                              hipStream_t stream) {
  const float* z   = (const float*)d_in[0];
  const float* h0  = (const float*)d_in[1];
  const float* Wih = (const float*)d_in[2];
  const float* Whh = (const float*)d_in[3];
  const float* bih = (const float*)d_in[4];
  const float* bhh = (const float*)d_in[5];
  float* out = (float*)d_out;
  char* Hws = (char*)d_ws;   // 8 chunks x 32 KB = 256 KB (pre-swizzled)

  rsbc_recur<<<1, 512, 0, stream>>>(Wih, Whh, bih, bhh, h0, Hws);
  const int nrows = out_size / NTOP;   // 131072
  const int blocks = nrows / 64;       // 2048
  rsbc_gemm_sb<<<blocks, 512, 0, stream>>>(z, Hws, out);
}

// Round 8
// 322.834 us; speedup vs baseline: 1.9582x; 1.9500x over previous
//
#include <hip/hip_runtime.h>

#define NTOP 256

typedef __attribute__((ext_vector_type(8))) short bf16x8;
typedef __attribute__((ext_vector_type(4))) float f32x4;

// round-to-nearest-even split of fp32 into bf16 hi/lo, packed (hi<<16)|lo
__device__ inline unsigned int packbf(float x) {
  unsigned int u = __float_as_uint(x);
  unsigned int r = (u + 0x7fffu + ((u >> 16) & 1u)) & 0xffff0000u;
  float res = x - __uint_as_float(r);
  unsigned int u2 = __float_as_uint(res);
  unsigned int r2 = u2 + 0x7fffu + ((u2 >> 16) & 1u);
  return r | (r2 >> 16);
}

__device__ inline float tanh_fast(float x) {
  float e = __expf(2.f * x);
  return 1.f - 2.f / (e + 1.f);
}

template <int CTRL>
__device__ inline float dpp_f(float v) {
  return __int_as_float(__builtin_amdgcn_update_dpp(
      0, __float_as_int(v), CTRL, 0xf, 0xf, true));
}

// ---------------------------------------------------------------- K1
// R2 structure (best measured: 217 us): 1024 thr, j = tid>>2 (output),
// qt = tid&3 (k-quarter of 64), w[16] float4 (64 floats) per thread,
// 4 independent FMA chains, 1 barrier/step, per-step packbf export.
// NEW: amdgpu_waves_per_eu(4,4) pins the allocator to the 128-VGPR
// budget that actually holds w — R2's binary spilled w to scratch
// (VGPR_Count=48) and re-read 256 KB from L2 every step.
// Reduce via DPP quad-perm (VALU) instead of shfl_xor (LDS pipe).
__global__ __launch_bounds__(1024)
__attribute__((amdgpu_waves_per_eu(4, 4)))
void rsbc_recur(
    const float* __restrict__ Wih, const float* __restrict__ Whh,
    const float* __restrict__ bih, const float* __restrict__ bhh,
    const float* __restrict__ h0, unsigned int* __restrict__ Hpack) {
  __shared__ float hA[4][68], hB[4][68];
  const int tid = threadIdx.x;
  const int j = tid >> 2, qt = tid & 3, k0 = qt * 64;
  const float bj = bih[j] + bhh[j];

  float4 w[16];
  {
    const float4* wp = reinterpret_cast<const float4*>(Wih + j * NTOP + k0);
#pragma unroll
    for (int q = 0; q < 16; ++q) w[q] = wp[q];
  }
  if (tid < NTOP) hA[tid >> 6][tid & 63] = h0[tid];
  __syncthreads();

  // step 0: h1 = tanh(h0 @ Wih^T + b)
  {
    const float* hq = hA[qt];
    float a0 = 0.f, a1 = 0.f, a2 = 0.f, a3 = 0.f;
#pragma unroll
    for (int q = 0; q < 16; ++q) {
      float4 hv = *reinterpret_cast<const float4*>(hq + 4 * q);
      a0 = fmaf(hv.x, w[q].x, a0);
      a1 = fmaf(hv.y, w[q].y, a1);
      a2 = fmaf(hv.z, w[q].z, a2);
      a3 = fmaf(hv.w, w[q].w, a3);
    }
    float sv = (a0 + a1) + (a2 + a3);
    sv += dpp_f<0xB1>(sv);  // + lane^1 (quad_perm 1,0,3,2)
    sv += dpp_f<0x4E>(sv);  // + lane^2 (quad_perm 2,3,0,1)
    if (qt == 0) {
      float v = tanh_fast(sv + bj);
      hB[j >> 6][j & 63] = v;
      Hpack[j] = packbf(v);            // H row 0
    }
  }
  // Wc = W_ih + W_hh
  {
    const float4* wq = reinterpret_cast<const float4*>(Whh + j * NTOP + k0);
#pragma unroll
    for (int q = 0; q < 16; ++q) {
      float4 t = wq[q];
      w[q].x += t.x; w[q].y += t.y; w[q].z += t.z; w[q].w += t.w;
    }
  }
  __syncthreads();

#pragma unroll 1
  for (int s = 1; s < 255; ++s) {
    const float(*hr)[68] = (s & 1) ? hB : hA;
    float(*hw)[68] = (s & 1) ? hA : hB;
    const float* hq = hr[qt];
    float a0 = 0.f, a1 = 0.f, a2 = 0.f, a3 = 0.f;
#pragma unroll
    for (int q = 0; q < 16; ++q) {
      float4 hv = *reinterpret_cast<const float4*>(hq + 4 * q);
      a0 = fmaf(hv.x, w[q].x, a0);
      a1 = fmaf(hv.y, w[q].y, a1);
      a2 = fmaf(hv.z, w[q].z, a2);
      a3 = fmaf(hv.w, w[q].w, a3);
    }
    float sv = (a0 + a1) + (a2 + a3);
    sv += dpp_f<0xB1>(sv);
    sv += dpp_f<0x4E>(sv);
    if (qt == 0) {
      float v = tanh_fast(sv + bj);
      hw[j >> 6][j & 63] = v;
      Hpack[s * NTOP + j] = packbf(v); // H row s
    }
    __syncthreads();
  }
}

// ---------------------------------------------------------------- K2
// R2's K2 verbatim (best measured: ~118 us): bf16x3 MFMA GEMM
// (Z @ H^T) + sigmoid + stick-breaking, 512 thr (8 waves 2x4), BM=128,
// N=256, K in 4 chunks of 64, 144-B LDS row stride (conflict-light),
// loads-before-barrier pipelining, LDS eta epilogue with 4-thread/row
// segmented cumprod, full-line float4 stores.
// NEW: amdgpu_waves_per_eu(2,2) — LDS already caps at 1 block/CU
// (= 2 waves/EU), so this only raises the register budget to 256 and
// eliminates the scratch spill traffic (R7: WRITE_SIZE 10x output).
__global__ __launch_bounds__(512)
__attribute__((amdgpu_waves_per_eu(2, 2)))
void rsbc_gemm_sb(
    const float* __restrict__ z, const unsigned int* __restrict__ Hpack,
    float* __restrict__ out) {
  constexpr int AS = 72;   // A row stride (bf16 elems), 144 B
  constexpr int BS = 72;   // B row stride
  constexpr int ES = 260;  // eta row stride (floats)
  __shared__ __align__(16) char smem[135168];
  __shared__ float logtab[256];
  ushort* Ahi = reinterpret_cast<ushort*>(smem);
  ushort* Alo = Ahi + 128 * AS;
  ushort* Bhi = Alo + 128 * AS;
  ushort* Blo = Bhi + 256 * BS;
  float* eta = reinterpret_cast<float*>(smem);
  float* segT = eta + 128 * ES;

  const int tid = threadIdx.x;
  const size_t row0 = (size_t)blockIdx.x * 128;
  const int wid = tid >> 6, lane = tid & 63;
  const int wr = wid >> 2, wc = wid & 3;
  const int l15 = lane & 15, l4 = lane >> 4;

  if (tid < 255) logtab[tid] = logf((float)(255 - tid));

  f32x4 acc[4][4];
#pragma unroll
  for (int mt = 0; mt < 4; ++mt)
#pragma unroll
    for (int nt = 0; nt < 4; ++nt) acc[mt][nt] = (f32x4){0.f, 0.f, 0.f, 0.f};

  for (int kc = 0; kc < 4; ++kc) {
    const int kb = kc * 64;
    // ---- global loads into regs (issued before barrier: overlap compute)
    float4 zreg[4];
#pragma unroll
    for (int it = 0; it < 4; ++it) {
      int idx = tid + 512 * it;        // 0..2047
      int r = idx >> 4, q = idx & 15;  // r 0..127
      zreg[it] = *reinterpret_cast<const float4*>(
          z + (row0 + r) * NTOP + kb + 4 * q);
    }
    uint4 hreg[8];
#pragma unroll
    for (int it = 0; it < 8; ++it) {
      int idx = tid + 512 * it;        // 0..4095
      int r = idx >> 4, q = idx & 15;  // r 0..255
      hreg[it] = (r < 255)
                     ? *reinterpret_cast<const uint4*>(
                           Hpack + r * NTOP + kb + 4 * q)
                     : make_uint4(0u, 0u, 0u, 0u);
    }
    __syncthreads();                   // previous chunk's frag reads done
    // ---- convert + LDS write
#pragma unroll
    for (int it = 0; it < 4; ++it) {
      int idx = tid + 512 * it;
      int r = idx >> 4, q = idx & 15;
      float4 v = zreg[it];
      unsigned int p0 = packbf(v.x), p1 = packbf(v.y),
                   p2 = packbf(v.z), p3 = packbf(v.w);
      *reinterpret_cast<ushort4*>(&Ahi[r * AS + 4 * q]) = make_ushort4(
          (ushort)(p0 >> 16), (ushort)(p1 >> 16),
          (ushort)(p2 >> 16), (ushort)(p3 >> 16));
      *reinterpret_cast<ushort4*>(&Alo[r * AS + 4 * q]) = make_ushort4(
          (ushort)(p0 & 0xffff), (ushort)(p1 & 0xffff),
          (ushort)(p2 & 0xffff), (ushort)(p3 & 0xffff));
    }
#pragma unroll
    for (int it = 0; it < 8; ++it) {
      int idx = tid + 512 * it;
      int r = idx >> 4, q = idx & 15;
      uint4 hv = hreg[it];
      *reinterpret_cast<ushort4*>(&Bhi[r * BS + 4 * q]) = make_ushort4(
          (ushort)(hv.x >> 16), (ushort)(hv.y >> 16),
          (ushort)(hv.z >> 16), (ushort)(hv.w >> 16));
      *reinterpret_cast<ushort4*>(&Blo[r * BS + 4 * q]) = make_ushort4(
          (ushort)(hv.x & 0xffff), (ushort)(hv.y & 0xffff),
          (ushort)(hv.z & 0xffff), (ushort)(hv.w & 0xffff));
    }
    __syncthreads();                   // staging visible
    // ---- compute: 2 k-steps of K=32
#pragma unroll
    for (int ks = 0; ks < 2; ++ks) {
      const int ko = ks * 32 + l4 * 8; // k elem offset within chunk row
      bf16x8 afh[4], afl[4], bfh[4], bfl[4];
#pragma unroll
      for (int mt = 0; mt < 4; ++mt) {
        int r = 64 * wr + 16 * mt + l15;
        afh[mt] = *reinterpret_cast<const bf16x8*>(&Ahi[r * AS + ko]);
        afl[mt] = *reinterpret_cast<const bf16x8*>(&Alo[r * AS + ko]);
      }
#pragma unroll
      for (int nt = 0; nt < 4; ++nt) {
        int n = 64 * wc + 16 * nt + l15;
        bfh[nt] = *reinterpret_cast<const bf16x8*>(&Bhi[n * BS + ko]);
        bfl[nt] = *reinterpret_cast<const bf16x8*>(&Blo[n * BS + ko]);
      }
#pragma unroll
      for (int mt = 0; mt < 4; ++mt)
#pragma unroll
        for (int nt = 0; nt < 4; ++nt) {
          acc[mt][nt] = __builtin_amdgcn_mfma_f32_16x16x32_bf16(
              afh[mt], bfh[nt], acc[mt][nt], 0, 0, 0);
          acc[mt][nt] = __builtin_amdgcn_mfma_f32_16x16x32_bf16(
              afh[mt], bfl[nt], acc[mt][nt], 0, 0, 0);
          acc[mt][nt] = __builtin_amdgcn_mfma_f32_16x16x32_bf16(
              afl[mt], bfh[nt], acc[mt][nt], 0, 0, 0);
        }
    }
  }
  __syncthreads();                     // frag reads done; smem becomes eta

  // ---- eta = sigmoid(logits) -> LDS
  // C/D layout (16x16x32): col = lane&15, row = (lane>>4)*4 + reg
#pragma unroll
  for (int mt = 0; mt < 4; ++mt) {
    int rbase = 64 * wr + 16 * mt + 4 * l4;
#pragma unroll
    for (int nt = 0; nt < 4; ++nt) {
      int c = 64 * wc + 16 * nt + l15;
#pragma unroll
      for (int i = 0; i < 4; ++i) {
        float x = acc[mt][nt][i];
        eta[(rbase + i) * ES + c] = 1.f / (1.f + __expf(-x));
      }
    }
  }
  __syncthreads();

  // ---- stick-breaking: 4 threads per row, segmented cumprod
  const int r = tid >> 2, qk = tid & 3;
  const int kbeg = 64 * qk, kend = (qk == 3) ? 255 : 64 * qk + 64;
  float* er = &eta[r * ES];
  {
    float cp = 1.f;
#pragma unroll 4
    for (int k = kbeg; k < kend; ++k) {
      float x = er[k] - logtab[k];
      float zc = 1.f / (1.f + __expf(-x));
      zc = fminf(fmaxf(zc, 1.1754943508222875e-38f), 0.99999988079071045f);
      er[k] = zc * cp;
      cp *= 1.f - zc;
    }
    segT[r * 4 + qk] = cp;
  }
  __syncthreads();
  {
    float p = 1.f;
    if (qk > 0) p *= segT[r * 4 + 0];
    if (qk > 1) p *= segT[r * 4 + 1];
    if (qk > 2) p *= segT[r * 4 + 2];
    if (qk > 0) {
#pragma unroll 4
      for (int k = kbeg; k < kend; ++k) er[k] *= p;
    }
    if (qk == 3) er[255] = p * segT[r * 4 + 3];
  }
  __syncthreads();

  // ---- coalesced store: 128 rows x 64 float4
#pragma unroll
  for (int it = 0; it < 16; ++it) {
    int idx = tid + 512 * it;          // 0..8191
    int rr = idx >> 6, cq = idx & 63;
    float4 vv = *reinterpret_cast<const float4*>(&eta[rr * ES + 4 * cq]);
    *reinterpret_cast<float4*>(&out[(row0 + rr) * NTOP + 4 * cq]) = vv;
  }
}

// ---------------------------------------------------------------- launch
extern "C" void kernel_launch(void* const* d_in, const int* in_sizes, int n_in,
                              void* d_out, int out_size, void* d_ws, size_t ws_size,
                              hipStream_t stream) {
  const float* z   = (const float*)d_in[0];
  const float* h0  = (const float*)d_in[1];
  const float* Wih = (const float*)d_in[2];
  const float* Whh = (const float*)d_in[3];
  const float* bih = (const float*)d_in[4];
  const float* bhh = (const float*)d_in[5];
  float* out = (float*)d_out;
  unsigned int* Hpack = (unsigned int*)d_ws;  // 255*256 uint32

  rsbc_recur<<<1, 1024, 0, stream>>>(Wih, Whh, bih, bhh, h0, Hpack);
  const int nrows = out_size / NTOP;          // 131072
  const int blocks = nrows / 128;             // 1024
  rsbc_gemm_sb<<<blocks, 512, 0, stream>>>(z, Hpack, out);
}